// Round 18
// baseline (46.048 us; speedup 1.0000x reference)
//
#include <hip/hip_runtime.h>

#define MDIM 4096
#define NDIM 4096
#define NCOEF 768
#define ALPHA 16.0f
#define PANEL_I8 (12 * 16384)      // bytes per 256-row/col panel (12 K-slabs x 16 KB)

typedef __attribute__((ext_vector_type(4))) int   i32x4;
typedef __attribute__((ext_vector_type(4))) float f32x4;

__device__ __forceinline__ void glds16c(const char* src, char* dst) {
    __builtin_amdgcn_global_load_lds(
        (const __attribute__((address_space(1))) void*)src,
        (__attribute__((address_space(3))) void*)dst, 16, 0, 0);
}

// ---- kernel 1: materialize U,V as INT8 in panel/chunk layout (meta fused) ----
// (unchanged from R17: 768 blocks, self-contained dedup + maxdw + quant)
__global__ __launch_bounds__(256) void fill_uv(
    const int* __restrict__ fidx, const float* __restrict__ dw,
    char* __restrict__ U8, char* __restrict__ V8, float* __restrict__ csp)
{
    __shared__ int idx_s[NCOEF];
    __shared__ float red[4];
    __shared__ int dup[16];
    __shared__ float su_l[16], sv_l[16];
    const int b = blockIdx.x;
    const int panel = b / 48;
    const int rem = b - panel * 48;
    const int kt = rem >> 2;
    const int k16 = rem & 3;
    const int p0 = kt * 64 + (k16 << 4);
    const int t = threadIdx.x;
    float m = 0.0f;
    #pragma unroll
    for (int j = 0; j < 3; ++j) {
        idx_s[t + (j << 8)] = fidx[t + (j << 8)];
        m = fmaxf(m, fabsf(dw[t + (j << 8)]));
    }
    if (t < 16) dup[t] = 0;
    #pragma unroll
    for (int off = 32; off > 0; off >>= 1) m = fmaxf(m, __shfl_xor(m, off));
    if ((t & 63) == 0) red[t >> 6] = m;
    __syncthreads();
    const float maxdw = fmaxf(fmaxf(red[0], red[1]), fmaxf(red[2], red[3]));
    {   // dedup (last-write-wins): 16 threads per coef scan 48 q's each
        const int ci = t >> 4;
        const int pci = p0 + ci;
        const int myidx = idx_s[pci];
        const int q0 = (t & 15) * 48;
        int found = 0;
        #pragma unroll
        for (int s = 0; s < 48; ++s) {
            const int q = q0 + s;
            found |= (q > pci) & (idx_s[q] == myidx);
        }
        if (found) dup[ci] = 1;
    }
    __syncthreads();
    const float s0 = 0.015625f;
    const float s1 = 0.022097086912079612f;
    const float Vmax = ALPHA * maxdw * s1;
    const float isV = (Vmax > 0.0f) ? (127.0f / Vmax) : 0.0f;
    if (t < 16) {
        const int p = p0 + t;
        const int idx = idx_s[p];
        const int r = idx >> 12;
        const int c = idx & (NDIM - 1);
        su_l[t] = ((r == 0) ? s0 : s1) * (127.0f / s1);
        sv_l[t] = (dup[t] ? 0.0f : 1.0f) * ALPHA * dw[p] * ((c == 0) ? s0 : s1) * isV;
    }
    if (b == 0 && t == 0) csp[0] = (s1 / 127.0f) * (Vmax / 127.0f);
    __syncthreads();
    const unsigned tt = 2u * (unsigned)((panel << 8) + t) + 1u;
    const float wrev = 1.0f / 16384.0f;
    unsigned wu[4] = {0, 0, 0, 0}, wv[4] = {0, 0, 0, 0};
    #pragma unroll
    for (int j = 0; j < 16; ++j) {
        const int idx = idx_s[p0 + j];
        const unsigned nu = (tt * (unsigned)(idx >> 12)) & 16383u;
        const unsigned nv = (tt * (unsigned)(idx & (NDIM - 1))) & 16383u;
        const int qu = (int)rintf(su_l[j] * __builtin_amdgcn_cosf((float)nu * wrev));
        const int qv = (int)rintf(sv_l[j] * __builtin_amdgcn_cosf((float)nv * wrev));
        wu[j >> 2] |= (unsigned)(qu & 255) << ((j & 3) * 8);
        wv[j >> 2] |= (unsigned)(qv & 255) << ((j & 3) * 8);
    }
    const size_t off = ((size_t)(panel * 12 + kt) * 1024 + (size_t)(k16 << 8) + t) << 4;
    *(uint4*)(U8 + off) = make_uint4(wu[0], wu[1], wu[2], wu[3]);
    *(uint4*)(V8 + off) = make_uint4(wv[0], wv[1], wv[2], wv[3]);
}

// ---- kernel 2: out = W + CS*(U8 @ V8^T), TWO-TILE pipeline ----
// Block owns two 256x128 tiles (same A-panel, bx = 2bxp / 2bxp+1). One
// continuous 24-iter K-pipeline (4 bufs, depth-2, 1 barrier/iter, counted
// vmcnt audited per iter). Iters 12-19 carry tile-A's epilogue inline:
// {L-write chunk c | W-load c} pre-barrier, {L-read + add + store} post-
// COMPUTE -> tile A's ENTIRE epilogue HBM traffic (W-read + out-write)
// overlaps tile B's MFMA/LDS work. L = 3-region rotation (reuse distance 3
// => barrier-separated). Tail: exposed epilogue-B only (R16 proven form).
__global__ __launch_bounds__(512, 1) void gemm_kernel(
    const float* __restrict__ W,
    const char* __restrict__ U8,
    const char* __restrict__ V8,
    const float* __restrict__ csp,
    float* __restrict__ out)
{
    __shared__ char SM[148992];          // 64K As + 32K Bs + 3x16896 L
    char* const As = SM;                 // 4 bufs x 16384 B
    char* const Bs = SM + 65536;         // 4 bufs x 8192 B
    float* const L = (float*)(SM + 98304);   // 3 regions x 4224 f32

    const int tid = threadIdx.x;         // 0..511
    const int lane = tid & 63;
    const int wave = tid >> 6;           // 0..7

    // XCD rect swizzle: 256 blocks, 8 XCDs, 4(by) x 8(bxp) rect per XCD.
    const int bid = blockIdx.x;
    const int xcd = bid & 7;
    const int local = bid >> 3;
    const int by = ((xcd >> 1) << 2) + (local >> 3);   // 0..15
    const int bxp = ((xcd & 1) << 3) + (local & 7);    // 0..15
    const int wr = wave >> 2;            // 0..1
    const int wc = wave & 3;             // 0..3
    const int fr = lane & 15;
    const int fks = lane >> 4;

    const char* uPan = U8 + (size_t)by * PANEL_I8;
    const char* vPanBase = V8 + (size_t)bxp * PANEL_I8;
    const float CS = *csp;

    i32x4 accA[8][2] = {};
    i32x4 accB[8][2] = {};
    float4 wreg[2][2];

    // LDS frag offsets (bytes): A chunk = k16*256+row, B chunk' = k16*128+col
    const int aO = (fks << 12) + ((wr * 128 + fr) << 4);
    const int bO = (fks << 11) + (((wc << 5) + fr) << 4);

    // epilogue coords
    const int erowBase = by << 8;
    const int bcolA = bxp << 8;              // tile A cols [bcolA, +128)
    const int bcolB = bcolA + 128;
    const int c4 = (tid & 31) << 2;          // f32 col offset within tile
    const int rsub = tid >> 5;               // 0..15

    // STAGE slab s (0..11 = tile A, 12..23 = tile B; A data identical):
    // A: 16 KB (2 glds/thread), B: 8 KB half-panel (1 glds/thread).
#define STAGE(s) do {                                                        \
        const int jA = (s) % 12;                                             \
        const char* uS = uPan + ((size_t)jA << 14);                          \
        char* aD = As + (((s) & 3) << 14) + (wave << 10);                    \
        glds16c(uS + (tid << 4), aD);                                        \
        glds16c(uS + 8192 + (tid << 4), aD + 8192);                          \
        const char* vS = vPanBase + ((size_t)jA << 14) + ((tid >> 7) << 12)  \
                         + (((s) >= 12) ? 2048 : 0) + ((tid & 127) << 4);    \
        glds16c(vS, Bs + (((s) & 3) << 13) + (wave << 10));                  \
    } while (0)

#define COMPUTE(buf, ACC) do {                                               \
        i32x4 a[8], b[2];                                                    \
        _Pragma("unroll")                                                    \
        for (int fm = 0; fm < 8; ++fm)                                       \
            a[fm] = *(const i32x4*)(As + (buf) * 16384 + aO + fm * 256);     \
        _Pragma("unroll")                                                    \
        for (int fn = 0; fn < 2; ++fn)                                       \
            b[fn] = *(const i32x4*)(Bs + (buf) * 8192 + bO + fn * 256);      \
        _Pragma("unroll")                                                    \
        for (int fm = 0; fm < 8; ++fm)                                       \
            _Pragma("unroll")                                                \
            for (int fn = 0; fn < 2; ++fn)                                   \
                ACC[fm][fn] = __builtin_amdgcn_mfma_i32_16x16x64_i8(         \
                    b[fn], a[fm], ACC[fm][fn], 0, 0, 0);                     \
    } while (0)

    // chunk c: tile rows [32c,32c+32); owner wr == c>>2; acc pair (c&3)*2
#define LWRITE(C, R, ACC) do {                                               \
        if (wr == ((C) >> 2)) {                                              \
            _Pragma("unroll")                                                \
            for (int f2 = 0; f2 < 2; ++f2)                                   \
                _Pragma("unroll")                                            \
                for (int fn = 0; fn < 2; ++fn) {                             \
                    f32x4 v;                                                 \
                    _Pragma("unroll")                                        \
                    for (int jj = 0; jj < 4; ++jj)                           \
                        v[jj] = CS * (float)ACC[((C) & 3) * 2 + f2][fn][jj]; \
                    *(f32x4*)(L + (R) * 4224 + (f2 * 16 + fr) * 132          \
                              + (wc << 5) + fn * 16 + (fks << 2)) = v;       \
                }                                                            \
        }                                                                    \
    } while (0)

#define WLOAD(C, SLOT, BCOL) do {                                            \
        _Pragma("unroll")                                                    \
        for (int i2 = 0; i2 < 2; ++i2)                                       \
            wreg[SLOT][i2] = *(const float4*)(W                              \
                + (size_t)(erowBase + (C) * 32 + i2 * 16 + rsub) * NDIM      \
                + (BCOL) + c4);                                              \
    } while (0)

#define STORE(C, R, SLOT, BCOL) do {                                         \
        _Pragma("unroll")                                                    \
        for (int i2 = 0; i2 < 2; ++i2) {                                     \
            const int rl = i2 * 16 + rsub;                                   \
            const size_t o = (size_t)(erowBase + (C) * 32 + rl) * NDIM       \
                             + (BCOL) + c4;                                  \
            const f32x4 l4 = *(const f32x4*)(L + (R) * 4224 + rl * 132 + c4);\
            float4 r4;                                                       \
            r4.x = wreg[SLOT][i2].x + l4[0];                                 \
            r4.y = wreg[SLOT][i2].y + l4[1];                                 \
            r4.z = wreg[SLOT][i2].z + l4[2];                                 \
            r4.w = wreg[SLOT][i2].w + l4[3];                                 \
            *(float4*)(out + o) = r4;                                        \
        }                                                                    \
    } while (0)

#define VW(n) asm volatile("s_waitcnt vmcnt(" #n ")" ::: "memory")

    // per-iter: [STAGE(i+2)] [LWRITE/WLOAD cL=i-12] VW(NC) lgkm BAR
    //           COMPUTE(i&3) [VW(NW) STORE cS=i-13]
#define ITER(I, NC_, NW_, ACC) do {                                          \
        if ((I) <= 21) STAGE((I) + 2);                                       \
        if ((I) >= 12 && (I) <= 19) {                                        \
            LWRITE((I) - 12, ((I) - 12) % 3, accA);                          \
            WLOAD((I) - 12, ((I) - 12) & 1, bcolA);                          \
        }                                                                    \
        VW(NC_);                                                             \
        asm volatile("s_waitcnt lgkmcnt(0)" ::: "memory");                   \
        __builtin_amdgcn_s_barrier();                                        \
        asm volatile("" ::: "memory");                                       \
        COMPUTE((I) & 3, ACC);                                               \
        if ((I) >= 13 && (I) <= 20) {                                        \
            VW(NW_);                                                         \
            STORE((I) - 13, ((I) - 13) % 3, ((I) - 13) & 1, bcolA);          \
        }                                                                    \
    } while (0)

    STAGE(0); STAGE(1);
    ITER(0, 6, 0, accA);  ITER(1, 6, 0, accA);  ITER(2, 6, 0, accA);
    ITER(3, 6, 0, accA);  ITER(4, 6, 0, accA);  ITER(5, 6, 0, accA);
    ITER(6, 6, 0, accA);  ITER(7, 6, 0, accA);  ITER(8, 6, 0, accA);
    ITER(9, 6, 0, accA);  ITER(10, 6, 0, accA); ITER(11, 6, 0, accA);
    ITER(12, 8, 0, accB); ITER(13, 10, 5, accB); ITER(14, 14, 7, accB);
    ITER(15, 16, 7, accB); ITER(16, 16, 7, accB); ITER(17, 16, 7, accB);
    ITER(18, 16, 7, accB); ITER(19, 16, 7, accB); ITER(20, 14, 5, accB);
    ITER(21, 12, 5, accB); ITER(22, 5, 0, accB); ITER(23, 0, 0, accB);

    // ---- tail: exposed epilogue for tile B (R16-style, 2-region) ----
    WLOAD(0, 0, bcolB);
    LWRITE(0, 0, accB);
    #pragma unroll
    for (int c = 0; c < 8; ++c) {
        __syncthreads();
        if (c < 7) {
            WLOAD(c + 1, (c + 1) & 1, bcolB);
            LWRITE(c + 1, (c + 1) & 1, accB);
        }
        STORE(c, c & 1, c & 1, bcolB);
    }
#undef STAGE
#undef COMPUTE
#undef LWRITE
#undef WLOAD
#undef STORE
#undef VW
#undef ITER
}

extern "C" void kernel_launch(void* const* d_in, const int* in_sizes, int n_in,
                              void* d_out, int out_size, void* d_ws, size_t ws_size,
                              hipStream_t stream) {
    const float* weight = (const float*)d_in[0];
    const float* dw     = (const float*)d_in[1];
    const int*   fidx   = (const int*)d_in[2];
    float* out = (float*)d_out;

    char* ws = (char*)d_ws;
    char* U8 = ws;                               // 3,145,728 B
    char* V8 = ws + 3145728;                     // 3,145,728 B
    float* csp = (float*)(ws + 2 * 3145728);

    fill_uv<<<16 * 48, 256, 0, stream>>>(fidx, dw, U8, V8, csp);
    gemm_kernel<<<256, 512, 0, stream>>>(weight, U8, V8, csp, out);
}